// Round 8
// baseline (89.602 us; speedup 1.0000x reference)
//
#include <hip/hip_runtime.h>
#include <math.h>

#define NPTS 10000
#define XPT 8              // x-points per thread in pass A (all scalar SP pipe)
#define AXCH 5             // 5 * 256 * 8 = 10240 >= 10000
#define NS 50              // slices
#define SLICE 200          // NPTS / NS

// Monotone u16 encode of m (range [-32,32), granularity 2^-10), floor-rounded.
// enc monotone => the slice holding the true global max always has enc == qmax;
// any other slice with enc == qmax is rescanned exactly and loses. Clamps are
// safe: clamped slices just become (correctly rescanned) candidates.
__device__ __forceinline__ unsigned short enc_q(float m) {
    int q = (int)floorf((m + 32.0f) * 1024.0f);
    q = q < 0 ? 0 : (q > 65535 ? 65535 : q);
    return (unsigned short)q;
}

// ---------------------------------------------------------------------------
// Pass A: per (combo, slice, x-chunk) max of m_j = dot(x,y_j) - 0.5*|y_j|^2
// (equiv. min d2). ALL-SCALAR fmaf/max3 (PKFMA removed: pk_fma_f32 runs on the
// half-width FP64 pipe and was the R4-R7 bottleneck). XPT=8 amortizes each LDS
// broadcast pair over 16 lane-pairs -> LDS ~11.5us < VALU floor ~17.8us.
// Stores u16 partials TRANSPOSED wsQ[c][n][s] so pass B reads are contiguous.
// ---------------------------------------------------------------------------
__global__ __launch_bounds__(256, 4) void knn_max(
    const float* __restrict__ pred_pts, const float* __restrict__ targ_pts,
    unsigned short* __restrict__ wsQ)
{
    const int c   = blockIdx.z;
    const int dir = c >> 1, b = c & 1;
    const float* xp = (dir == 0 ? targ_pts : pred_pts) + (size_t)b * NPTS * 3;
    const float* yp = (dir == 0 ? pred_pts : targ_pts) + (size_t)b * NPTS * 3;
    const int s = blockIdx.y;
    const int base = blockIdx.x * (256 * XPT) + threadIdx.x;

    __shared__ float4 sy[SLICE];               // 3.2 KB

    float xx[XPT][3];
#pragma unroll
    for (int k = 0; k < XPT; ++k) {
        const int n = base + k * 256;
        const int nn = (n < NPTS) ? n : (NPTS - 1);   // clamp; discard on store
        xx[k][0] = xp[nn * 3 + 0];
        xx[k][1] = xp[nn * 3 + 1];
        xx[k][2] = xp[nn * 3 + 2];
    }
    float best[XPT];
#pragma unroll
    for (int k = 0; k < XPT; ++k) best[k] = -1e30f;

    const int js = s * SLICE;
    for (int j = threadIdx.x; j < SLICE; j += 256) {
        const float a  = yp[(js + j) * 3 + 0];
        const float bb = yp[(js + j) * 3 + 1];
        const float cc = yp[(js + j) * 3 + 2];
        // hy chain with explicit fmaf so finalize reproduces it bit-exactly.
        sy[j] = make_float4(a, bb, cc, -0.5f * fmaf(cc, cc, fmaf(bb, bb, a * a)));
    }
    __syncthreads();

#pragma unroll 4
    for (int j = 0; j < SLICE; j += 2) {
        const float4 Y0 = sy[j];               // broadcast: conflict-free
        const float4 Y1 = sy[j + 1];
#pragma unroll
        for (int k = 0; k < XPT; ++k) {
            const float ma = fmaf(xx[k][0], Y0.x,
                             fmaf(xx[k][1], Y0.y,
                             fmaf(xx[k][2], Y0.z, Y0.w)));
            const float mb = fmaf(xx[k][0], Y1.x,
                             fmaf(xx[k][1], Y1.y,
                             fmaf(xx[k][2], Y1.z, Y1.w)));
            best[k] = fmaxf(fmaxf(best[k], ma), mb);   // -> v_max3_f32
        }
    }

#pragma unroll
    for (int k = 0; k < XPT; ++k) {
        const int n = base + k * 256;
        if (n < NPTS)
            wsQ[((size_t)c * NPTS + n) * NS + s] = enc_q(best[k]);
    }
}

// ---------------------------------------------------------------------------
// Pass B: one 64-lane wave per x-point (8 waves / 512-thread block).
//   1) lane s reads u16 partial (contiguous 100 B per wave), wave-max
//   2) rescan every slice with enc == qmax (provably includes the winner;
//      usually exactly 1). Ascending s + ascending in-lane j + strict > +
//      cross-lane tie->smaller j == exact first-occurrence argmax.
//   3) lane 0: Welsch + normal-cosine terms; block-reduce to float2.
// ---------------------------------------------------------------------------
__global__ __launch_bounds__(512) void finalize(
    const float* __restrict__ pred_pts, const float* __restrict__ pred_nrm,
    const float* __restrict__ targ_pts, const float* __restrict__ targ_nrm,
    const unsigned short* __restrict__ wsQ, float2* __restrict__ wsB)
{
    const int c   = blockIdx.y;
    const int dir = c >> 1, b = c & 1;
    const float* xp = (dir == 0 ? targ_pts : pred_pts) + (size_t)b * NPTS * 3;
    const float* xn = (dir == 0 ? targ_nrm : pred_nrm) + (size_t)b * NPTS * 3;
    const float* yp = (dir == 0 ? pred_pts : targ_pts) + (size_t)b * NPTS * 3;
    const float* yn = (dir == 0 ? pred_nrm : targ_nrm) + (size_t)b * NPTS * 3;

    const int lane = threadIdx.x & 63;
    const int wv   = threadIdx.x >> 6;
    const int n    = blockIdx.x * 8 + wv;      // 1250*8 = 10000 exactly

    int q = -1;
    if (lane < NS) q = wsQ[((size_t)c * NPTS + n) * NS + lane];
    int qmax = q;
#pragma unroll
    for (int w = 1; w < 64; w <<= 1)
        qmax = max(qmax, __shfl_xor(qmax, w));

    const float a  = xp[n * 3 + 0];            // wave-uniform -> scalarized
    const float bb = xp[n * 3 + 1];
    const float cc = xp[n * 3 + 2];

    float rb = -1e30f;
    int bidx = 1 << 30;
    for (int s = 0; s < NS; ++s) {
        if (__shfl(q, s) == qmax) {            // candidate slice: exact rescan
            const int jend = (s + 1) * SLICE;
            for (int j = s * SLICE + lane; j < jend; j += 64) {
                const float ya = yp[j * 3 + 0];
                const float yb = yp[j * 3 + 1];
                const float yc = yp[j * 3 + 2];
                const float hy = -0.5f * fmaf(yc, yc, fmaf(yb, yb, ya * ya));
                const float m  = fmaf(a, ya, fmaf(bb, yb, fmaf(cc, yc, hy)));
                if (m > rb) { rb = m; bidx = j; }   // in-lane: j ascending
            }
        }
    }
#pragma unroll
    for (int w = 1; w < 64; w <<= 1) {
        const float mo = __shfl_xor(rb, w);
        const int   jo = __shfl_xor(bidx, w);
        if (mo > rb || (mo == rb && jo < bidx)) { rb = mo; bidx = jo; }
    }

    float t0 = 0.f, t1 = 0.f;
    if (lane == 0) {
        const float hx = -0.5f * fmaf(cc, cc, fmaf(bb, bb, a * a));
        float d2 = -2.0f * (rb + hx);
        d2 = fmaxf(d2, 0.0f);
        const float w = __expf(-(d2 * d2) * (1.0f / 0.18f));   // 2*ALPHA^2
        t0 = w * d2;
        const float nx0 = xn[n * 3 + 0], nx1 = xn[n * 3 + 1], nx2 = xn[n * 3 + 2];
        const float ny0 = yn[(size_t)bidx * 3 + 0];
        const float ny1 = yn[(size_t)bidx * 3 + 1];
        const float ny2 = yn[(size_t)bidx * 3 + 2];
        const float nnx = fmaxf(sqrtf(nx0 * nx0 + nx1 * nx1 + nx2 * nx2), 1e-6f);
        const float nny = fmaxf(sqrtf(ny0 * ny0 + ny1 * ny1 + ny2 * ny2), 1e-6f);
        const float cosv = (nx0 * ny0 + nx1 * ny1 + nx2 * ny2) / (nnx * nny);
        t1 = 1.0f - fabsf(cosv);
    }

    __shared__ float r0[512], r1[512];
    r0[threadIdx.x] = t0;
    r1[threadIdx.x] = t1;
    __syncthreads();
    for (int st = 256; st > 0; st >>= 1) {
        if (threadIdx.x < st) {
            r0[threadIdx.x] += r0[threadIdx.x + st];
            r1[threadIdx.x] += r1[threadIdx.x + st];
        }
        __syncthreads();
    }
    if (threadIdx.x == 0)
        wsB[blockIdx.y * gridDim.x + blockIdx.x] = make_float2(r0[0], r1[0]);
}

// ---------------------------------------------------------------------------
// Final deterministic reduction of the 5000 block partials.
// ---------------------------------------------------------------------------
__global__ __launch_bounds__(256) void reduce_final(
    const float2* __restrict__ wsB, int nblocks, float* __restrict__ out)
{
    __shared__ float r0[256], r1[256];
    const int t = threadIdx.x;
    float s0 = 0.f, s1 = 0.f;
    for (int i = t; i < nblocks; i += 256) {
        const float2 v = wsB[i];
        s0 += v.x;
        s1 += v.y;
    }
    r0[t] = s0; r1[t] = s1;
    __syncthreads();
    for (int st = 128; st > 0; st >>= 1) {
        if (t < st) { r0[t] += r0[t + st]; r1[t] += r1[t + st]; }
        __syncthreads();
    }
    if (t == 0) {
        out[0] = 0.5f * r0[0];                 // mean over B=2 of per-batch sums
        out[1] = r1[0] * (1.0f / 20000.0f);    // mean over B*N, both dirs
    }
}

extern "C" void kernel_launch(void* const* d_in, const int* in_sizes, int n_in,
                              void* d_out, int out_size, void* d_ws, size_t ws_size,
                              hipStream_t stream)
{
    const float* pred_pts = (const float*)d_in[0];
    const float* pred_nrm = (const float*)d_in[1];
    const float* targ_pts = (const float*)d_in[2];
    const float* targ_nrm = (const float*)d_in[3];
    float* out = (float*)d_out;

    const int BXCH = NPTS / 8;           // 1250 blocks per combo in pass B

    unsigned short* wsQ = (unsigned short*)d_ws;    // 4*NPTS*NS u16 = 4.0 MB
    float2* wsB = (float2*)((char*)d_ws + (size_t)4 * NPTS * NS * sizeof(unsigned short));

    dim3 gA(AXCH, NS, 4);                // 1000 blocks
    knn_max<<<gA, 256, 0, stream>>>(pred_pts, targ_pts, wsQ);

    dim3 gB(BXCH, 4);
    finalize<<<gB, 512, 0, stream>>>(pred_pts, pred_nrm, targ_pts, targ_nrm,
                                     wsQ, wsB);

    reduce_final<<<1, 256, 0, stream>>>(wsB, BXCH * 4, out);
}

// Round 9
// 56.259 us; speedup vs baseline: 1.5927x; 1.5927x over previous
//
#include <hip/hip_runtime.h>
#include <math.h>

#define NPTS 10000
#define XPT 6              // x-points per thread (sweet spot: R2's 4 ok, 8+ taxed)
#define AXCH 7             // 7 * 256 * 6 = 10752 >= 10000
#define NS 25              // slices
#define SLICE 400          // NPTS / NS

// ---------------------------------------------------------------------------
// Pass A (R2-proven structure): per (combo, slice, x-chunk) max of
// m_j = dot(x,y_j) - 0.5*|y_j|^2 (equiv. min d2). All-scalar fmaf + max3.
// f32 partials stored coalesced in [c][s][n] layout (R2's store pattern).
// ---------------------------------------------------------------------------
__global__ __launch_bounds__(256) void knn_max(
    const float* __restrict__ pred_pts, const float* __restrict__ targ_pts,
    float* __restrict__ wsM)
{
    const int c   = blockIdx.z;
    const int dir = c >> 1, b = c & 1;
    const float* xp = (dir == 0 ? targ_pts : pred_pts) + (size_t)b * NPTS * 3;
    const float* yp = (dir == 0 ? pred_pts : targ_pts) + (size_t)b * NPTS * 3;
    const int s = blockIdx.y;
    const int base = blockIdx.x * (256 * XPT) + threadIdx.x;

    __shared__ float4 sy[SLICE];               // 6.4 KB

    float xx[XPT][3];
#pragma unroll
    for (int k = 0; k < XPT; ++k) {
        const int n = base + k * 256;
        const int nn = (n < NPTS) ? n : (NPTS - 1);   // clamp; discard on store
        xx[k][0] = xp[nn * 3 + 0];
        xx[k][1] = xp[nn * 3 + 1];
        xx[k][2] = xp[nn * 3 + 2];
    }
    float best[XPT];
#pragma unroll
    for (int k = 0; k < XPT; ++k) best[k] = -1e30f;

    const int js = s * SLICE;
    for (int j = threadIdx.x; j < SLICE; j += 256) {
        const float a  = yp[(js + j) * 3 + 0];
        const float bb = yp[(js + j) * 3 + 1];
        const float cc = yp[(js + j) * 3 + 2];
        // hy chain with explicit fmaf so finalize reproduces it bit-exactly.
        sy[j] = make_float4(a, bb, cc, -0.5f * fmaf(cc, cc, fmaf(bb, bb, a * a)));
    }
    __syncthreads();

#pragma unroll 4
    for (int j = 0; j < SLICE; j += 2) {
        const float4 Y0 = sy[j];               // broadcast: conflict-free
        const float4 Y1 = sy[j + 1];
#pragma unroll
        for (int k = 0; k < XPT; ++k) {
            const float ma = fmaf(xx[k][0], Y0.x,
                             fmaf(xx[k][1], Y0.y,
                             fmaf(xx[k][2], Y0.z, Y0.w)));
            const float mb = fmaf(xx[k][0], Y1.x,
                             fmaf(xx[k][1], Y1.y,
                             fmaf(xx[k][2], Y1.z, Y1.w)));
            best[k] = fmaxf(fmaxf(best[k], ma), mb);   // -> v_max3_f32
        }
    }

#pragma unroll
    for (int k = 0; k < XPT; ++k) {
        const int n = base + k * 256;
        if (n < NPTS)
            wsM[((size_t)c * NS + s) * NPTS + n] = best[k];   // coalesced
    }
}

// ---------------------------------------------------------------------------
// Pass B (R3-proven structure, ~7us): 8-lane group per x-point.
//   1) slice-select: strided direct loads (NO shfl loop), 3-step butterfly,
//      tie -> smaller s.
//   2) lane-parallel rescan of the winning slice (50 iters), identical fmaf
//      chain -> bit-consistent with pass A; strict > ascending j + cross-lane
//      tie -> smaller j == exact first-occurrence argmax.
//   3) lane 0: Welsch + normal-cosine terms; block-reduce to float2.
// ---------------------------------------------------------------------------
__global__ __launch_bounds__(256) void finalize(
    const float* __restrict__ pred_pts, const float* __restrict__ pred_nrm,
    const float* __restrict__ targ_pts, const float* __restrict__ targ_nrm,
    const float* __restrict__ wsM, float2* __restrict__ wsB)
{
    const int c   = blockIdx.y;
    const int dir = c >> 1, b = c & 1;
    const float* xp = (dir == 0 ? targ_pts : pred_pts) + (size_t)b * NPTS * 3;
    const float* xn = (dir == 0 ? targ_nrm : pred_nrm) + (size_t)b * NPTS * 3;
    const float* yp = (dir == 0 ? pred_pts : targ_pts) + (size_t)b * NPTS * 3;
    const float* yn = (dir == 0 ? pred_nrm : targ_nrm) + (size_t)b * NPTS * 3;

    const int lane = threadIdx.x & 7;
    const int n = blockIdx.x * 32 + (threadIdx.x >> 3);

    float t0 = 0.f, t1 = 0.f;
    if (n < NPTS) {
        // 1) slice select, lane-parallel strided loads
        float bm = -1e30f;
        int   bs = 1 << 30;
        for (int s = lane; s < NS; s += 8) {
            const float m = wsM[((size_t)c * NS + s) * NPTS + n];
            if (m > bm) { bm = m; bs = s; }    // in-lane: s ascending
        }
#pragma unroll
        for (int w = 1; w < 8; w <<= 1) {
            const float mo = __shfl_xor(bm, w);
            const int   so = __shfl_xor(bs, w);
            if (mo > bm || (mo == bm && so < bs)) { bm = mo; bs = so; }
        }
        // 2) rescan winning slice
        const float a  = xp[n * 3 + 0];
        const float bb = xp[n * 3 + 1];
        const float cc = xp[n * 3 + 2];
        const int j0 = bs * SLICE;
        float rb = -1e30f;
        int bidx = 1 << 30;
        for (int j = j0 + lane; j < j0 + SLICE; j += 8) {
            const float ya = yp[j * 3 + 0];
            const float yb = yp[j * 3 + 1];
            const float yc = yp[j * 3 + 2];
            const float hy = -0.5f * fmaf(yc, yc, fmaf(yb, yb, ya * ya));
            const float m  = fmaf(a, ya, fmaf(bb, yb, fmaf(cc, yc, hy)));
            if (m > rb) { rb = m; bidx = j; }  // in-lane: j ascending
        }
#pragma unroll
        for (int w = 1; w < 8; w <<= 1) {
            const float mo = __shfl_xor(rb, w);
            const int   jo = __shfl_xor(bidx, w);
            if (mo > rb || (mo == rb && jo < bidx)) { rb = mo; bidx = jo; }
        }
        // 3) terms on lane 0 only
        if (lane == 0) {
            const float hx = -0.5f * fmaf(cc, cc, fmaf(bb, bb, a * a));
            float d2 = -2.0f * (rb + hx);
            d2 = fmaxf(d2, 0.0f);
            const float w = __expf(-(d2 * d2) * (1.0f / 0.18f));  // 2*ALPHA^2
            t0 = w * d2;
            const float nx0 = xn[n * 3 + 0], nx1 = xn[n * 3 + 1], nx2 = xn[n * 3 + 2];
            const float ny0 = yn[(size_t)bidx * 3 + 0];
            const float ny1 = yn[(size_t)bidx * 3 + 1];
            const float ny2 = yn[(size_t)bidx * 3 + 2];
            const float nnx = fmaxf(sqrtf(nx0 * nx0 + nx1 * nx1 + nx2 * nx2), 1e-6f);
            const float nny = fmaxf(sqrtf(ny0 * ny0 + ny1 * ny1 + ny2 * ny2), 1e-6f);
            const float cosv = (nx0 * ny0 + nx1 * ny1 + nx2 * ny2) / (nnx * nny);
            t1 = 1.0f - fabsf(cosv);
        }
    }

    __shared__ float r0[256], r1[256];
    r0[threadIdx.x] = t0;
    r1[threadIdx.x] = t1;
    __syncthreads();
    for (int st = 128; st > 0; st >>= 1) {
        if (threadIdx.x < st) {
            r0[threadIdx.x] += r0[threadIdx.x + st];
            r1[threadIdx.x] += r1[threadIdx.x + st];
        }
        __syncthreads();
    }
    if (threadIdx.x == 0)
        wsB[blockIdx.y * gridDim.x + blockIdx.x] = make_float2(r0[0], r1[0]);
}

// ---------------------------------------------------------------------------
// Final deterministic reduction of the 1252 block partials.
// ---------------------------------------------------------------------------
__global__ __launch_bounds__(256) void reduce_final(
    const float2* __restrict__ wsB, int nblocks, float* __restrict__ out)
{
    __shared__ float r0[256], r1[256];
    const int t = threadIdx.x;
    float s0 = 0.f, s1 = 0.f;
    for (int i = t; i < nblocks; i += 256) {
        const float2 v = wsB[i];
        s0 += v.x;
        s1 += v.y;
    }
    r0[t] = s0; r1[t] = s1;
    __syncthreads();
    for (int st = 128; st > 0; st >>= 1) {
        if (t < st) { r0[t] += r0[t + st]; r1[t] += r1[t + st]; }
        __syncthreads();
    }
    if (t == 0) {
        out[0] = 0.5f * r0[0];                 // mean over B=2 of per-batch sums
        out[1] = r1[0] * (1.0f / 20000.0f);    // mean over B*N, both dirs
    }
}

extern "C" void kernel_launch(void* const* d_in, const int* in_sizes, int n_in,
                              void* d_out, int out_size, void* d_ws, size_t ws_size,
                              hipStream_t stream)
{
    const float* pred_pts = (const float*)d_in[0];
    const float* pred_nrm = (const float*)d_in[1];
    const float* targ_pts = (const float*)d_in[2];
    const float* targ_nrm = (const float*)d_in[3];
    float* out = (float*)d_out;

    const int BXCH = (NPTS + 31) / 32;   // 313 blocks per combo in pass B

    float* wsM = (float*)d_ws;           // 4*NS*NPTS f32 = 4.0 MB
    float2* wsB = (float2*)((char*)d_ws + (size_t)4 * NS * NPTS * sizeof(float));

    dim3 gA(AXCH, NS, 4);                // 700 blocks
    knn_max<<<gA, 256, 0, stream>>>(pred_pts, targ_pts, wsM);

    dim3 gB(BXCH, 4);
    finalize<<<gB, 256, 0, stream>>>(pred_pts, pred_nrm, targ_pts, targ_nrm,
                                     wsM, wsB);

    reduce_final<<<1, 256, 0, stream>>>(wsB, BXCH * 4, out);
}

// Round 10
// 49.482 us; speedup vs baseline: 1.8108x; 1.1370x over previous
//
#include <hip/hip_runtime.h>
#include <math.h>

#define NPTS 10000
#define XPT 4              // x-points per thread -- largest register-safe value
#define AXCH 10            // 10 * 256 * 4 = 10240 >= 10000
#define NS 50              // slices
#define SLICE 200          // NPTS / NS (even)

// ---------------------------------------------------------------------------
// Pass A (R2-proven inner loop, high-occupancy geometry): per (combo, slice,
// x-chunk) max of m_j = dot(x,y_j) - 0.5*|y_j|^2 (equiv. min d2). All-scalar
// fmaf + max3. 2000 blocks -> 31 waves/CU: VALU (18us/SIMD) and LDS broadcast
// (20.8us/CU at 8cyc/b128) fully overlapped. XPT=4 keeps live state ~22 regs
// -> no AGPR-shuffle tax (the R3-R9 XPT>=6 wall).
// ---------------------------------------------------------------------------
__global__ __launch_bounds__(256) void knn_max(
    const float* __restrict__ pred_pts, const float* __restrict__ targ_pts,
    float* __restrict__ wsM)
{
    const int c   = blockIdx.z;
    const int dir = c >> 1, b = c & 1;
    const float* xp = (dir == 0 ? targ_pts : pred_pts) + (size_t)b * NPTS * 3;
    const float* yp = (dir == 0 ? pred_pts : targ_pts) + (size_t)b * NPTS * 3;
    const int s = blockIdx.y;
    const int base = blockIdx.x * (256 * XPT) + threadIdx.x;

    __shared__ float4 sy[SLICE];               // 3.2 KB

    float xx[XPT][3];
#pragma unroll
    for (int k = 0; k < XPT; ++k) {
        const int n = base + k * 256;
        const int nn = (n < NPTS) ? n : (NPTS - 1);   // clamp; discard on store
        xx[k][0] = xp[nn * 3 + 0];
        xx[k][1] = xp[nn * 3 + 1];
        xx[k][2] = xp[nn * 3 + 2];
    }
    float best[XPT];
#pragma unroll
    for (int k = 0; k < XPT; ++k) best[k] = -1e30f;

    const int js = s * SLICE;
    for (int j = threadIdx.x; j < SLICE; j += 256) {
        const float a  = yp[(js + j) * 3 + 0];
        const float bb = yp[(js + j) * 3 + 1];
        const float cc = yp[(js + j) * 3 + 2];
        // hy chain with explicit fmaf so finalize reproduces it bit-exactly.
        sy[j] = make_float4(a, bb, cc, -0.5f * fmaf(cc, cc, fmaf(bb, bb, a * a)));
    }
    __syncthreads();

#pragma unroll 4
    for (int j = 0; j < SLICE; j += 2) {
        const float4 Y0 = sy[j];               // broadcast: conflict-free
        const float4 Y1 = sy[j + 1];
#pragma unroll
        for (int k = 0; k < XPT; ++k) {
            const float ma = fmaf(xx[k][0], Y0.x,
                             fmaf(xx[k][1], Y0.y,
                             fmaf(xx[k][2], Y0.z, Y0.w)));
            const float mb = fmaf(xx[k][0], Y1.x,
                             fmaf(xx[k][1], Y1.y,
                             fmaf(xx[k][2], Y1.z, Y1.w)));
            best[k] = fmaxf(fmaxf(best[k], ma), mb);   // -> v_max3_f32
        }
    }

#pragma unroll
    for (int k = 0; k < XPT; ++k) {
        const int n = base + k * 256;
        if (n < NPTS)
            wsM[((size_t)c * NS + s) * NPTS + n] = best[k];   // coalesced
    }
}

// ---------------------------------------------------------------------------
// Pass B (R3-proven structure): 8-lane group per x-point.
//   1) slice-select: strided direct loads, 3-step butterfly, tie -> smaller s.
//   2) lane-parallel rescan of the winning slice (25 iters), identical fmaf
//      chain -> bit-consistent with pass A; strict > ascending j + cross-lane
//      tie -> smaller j == exact first-occurrence argmax.
//   3) lane 0: Welsch + normal-cosine terms; block-reduce to float2.
// ---------------------------------------------------------------------------
__global__ __launch_bounds__(256) void finalize(
    const float* __restrict__ pred_pts, const float* __restrict__ pred_nrm,
    const float* __restrict__ targ_pts, const float* __restrict__ targ_nrm,
    const float* __restrict__ wsM, float2* __restrict__ wsB)
{
    const int c   = blockIdx.y;
    const int dir = c >> 1, b = c & 1;
    const float* xp = (dir == 0 ? targ_pts : pred_pts) + (size_t)b * NPTS * 3;
    const float* xn = (dir == 0 ? targ_nrm : pred_nrm) + (size_t)b * NPTS * 3;
    const float* yp = (dir == 0 ? pred_pts : targ_pts) + (size_t)b * NPTS * 3;
    const float* yn = (dir == 0 ? pred_nrm : targ_nrm) + (size_t)b * NPTS * 3;

    const int lane = threadIdx.x & 7;
    const int n = blockIdx.x * 32 + (threadIdx.x >> 3);

    float t0 = 0.f, t1 = 0.f;
    if (n < NPTS) {
        // 1) slice select, lane-parallel strided loads
        float bm = -1e30f;
        int   bs = 1 << 30;
        for (int s = lane; s < NS; s += 8) {
            const float m = wsM[((size_t)c * NS + s) * NPTS + n];
            if (m > bm) { bm = m; bs = s; }    // in-lane: s ascending
        }
#pragma unroll
        for (int w = 1; w < 8; w <<= 1) {
            const float mo = __shfl_xor(bm, w);
            const int   so = __shfl_xor(bs, w);
            if (mo > bm || (mo == bm && so < bs)) { bm = mo; bs = so; }
        }
        // 2) rescan winning slice
        const float a  = xp[n * 3 + 0];
        const float bb = xp[n * 3 + 1];
        const float cc = xp[n * 3 + 2];
        const int j0 = bs * SLICE;
        float rb = -1e30f;
        int bidx = 1 << 30;
        for (int j = j0 + lane; j < j0 + SLICE; j += 8) {
            const float ya = yp[j * 3 + 0];
            const float yb = yp[j * 3 + 1];
            const float yc = yp[j * 3 + 2];
            const float hy = -0.5f * fmaf(yc, yc, fmaf(yb, yb, ya * ya));
            const float m  = fmaf(a, ya, fmaf(bb, yb, fmaf(cc, yc, hy)));
            if (m > rb) { rb = m; bidx = j; }  // in-lane: j ascending
        }
#pragma unroll
        for (int w = 1; w < 8; w <<= 1) {
            const float mo = __shfl_xor(rb, w);
            const int   jo = __shfl_xor(bidx, w);
            if (mo > rb || (mo == rb && jo < bidx)) { rb = mo; bidx = jo; }
        }
        // 3) terms on lane 0 only
        if (lane == 0) {
            const float hx = -0.5f * fmaf(cc, cc, fmaf(bb, bb, a * a));
            float d2 = -2.0f * (rb + hx);
            d2 = fmaxf(d2, 0.0f);
            const float w = __expf(-(d2 * d2) * (1.0f / 0.18f));  // 2*ALPHA^2
            t0 = w * d2;
            const float nx0 = xn[n * 3 + 0], nx1 = xn[n * 3 + 1], nx2 = xn[n * 3 + 2];
            const float ny0 = yn[(size_t)bidx * 3 + 0];
            const float ny1 = yn[(size_t)bidx * 3 + 1];
            const float ny2 = yn[(size_t)bidx * 3 + 2];
            const float nnx = fmaxf(sqrtf(nx0 * nx0 + nx1 * nx1 + nx2 * nx2), 1e-6f);
            const float nny = fmaxf(sqrtf(ny0 * ny0 + ny1 * ny1 + ny2 * ny2), 1e-6f);
            const float cosv = (nx0 * ny0 + nx1 * ny1 + nx2 * ny2) / (nnx * nny);
            t1 = 1.0f - fabsf(cosv);
        }
    }

    __shared__ float r0[256], r1[256];
    r0[threadIdx.x] = t0;
    r1[threadIdx.x] = t1;
    __syncthreads();
    for (int st = 128; st > 0; st >>= 1) {
        if (threadIdx.x < st) {
            r0[threadIdx.x] += r0[threadIdx.x + st];
            r1[threadIdx.x] += r1[threadIdx.x + st];
        }
        __syncthreads();
    }
    if (threadIdx.x == 0)
        wsB[blockIdx.y * gridDim.x + blockIdx.x] = make_float2(r0[0], r1[0]);
}

// ---------------------------------------------------------------------------
// Final deterministic reduction of the 1252 block partials.
// ---------------------------------------------------------------------------
__global__ __launch_bounds__(256) void reduce_final(
    const float2* __restrict__ wsB, int nblocks, float* __restrict__ out)
{
    __shared__ float r0[256], r1[256];
    const int t = threadIdx.x;
    float s0 = 0.f, s1 = 0.f;
    for (int i = t; i < nblocks; i += 256) {
        const float2 v = wsB[i];
        s0 += v.x;
        s1 += v.y;
    }
    r0[t] = s0; r1[t] = s1;
    __syncthreads();
    for (int st = 128; st > 0; st >>= 1) {
        if (t < st) { r0[t] += r0[t + st]; r1[t] += r1[t + st]; }
        __syncthreads();
    }
    if (t == 0) {
        out[0] = 0.5f * r0[0];                 // mean over B=2 of per-batch sums
        out[1] = r1[0] * (1.0f / 20000.0f);    // mean over B*N, both dirs
    }
}

extern "C" void kernel_launch(void* const* d_in, const int* in_sizes, int n_in,
                              void* d_out, int out_size, void* d_ws, size_t ws_size,
                              hipStream_t stream)
{
    const float* pred_pts = (const float*)d_in[0];
    const float* pred_nrm = (const float*)d_in[1];
    const float* targ_pts = (const float*)d_in[2];
    const float* targ_nrm = (const float*)d_in[3];
    float* out = (float*)d_out;

    const int BXCH = (NPTS + 31) / 32;   // 313 blocks per combo in pass B

    float* wsM = (float*)d_ws;           // 4*NS*NPTS f32 = 4.0 MB (proven fit)
    float2* wsB = (float2*)((char*)d_ws + (size_t)4 * NS * NPTS * sizeof(float));

    dim3 gA(AXCH, NS, 4);                // 2000 blocks -> 31 waves/CU
    knn_max<<<gA, 256, 0, stream>>>(pred_pts, targ_pts, wsM);

    dim3 gB(BXCH, 4);
    finalize<<<gB, 256, 0, stream>>>(pred_pts, pred_nrm, targ_pts, targ_nrm,
                                     wsM, wsB);

    reduce_final<<<1, 256, 0, stream>>>(wsB, BXCH * 4, out);
}